// Round 1
// baseline (573.503 us; speedup 1.0000x reference)
//
#include <hip/hip_runtime.h>
#include <hip/hip_bf16.h>

#define B_ 4
#define T_ 1024
#define D_ 512
#define H_ 8
#define S_ 16
#define HD_ 64
#define ROWS 8
#define JT 128

// ---------------- params: centers, inv_var, eff_amps, inv_temp ----------------
__global__ void k_params(const float* __restrict__ base_centers,
                         const float* __restrict__ center_deltas,
                         const float* __restrict__ log_scales,
                         const float* __restrict__ log_amps,
                         const float* __restrict__ movement_param,
                         const float* __restrict__ temperature,
                         float* __restrict__ centers,
                         float* __restrict__ inv_var,
                         float* __restrict__ eff_amps,
                         float* __restrict__ inv_temp) {
  int tid = blockIdx.x * blockDim.x + threadIdx.x;
  float move = (1.f / (1.f + __expf(-movement_param[0]))) * 0.2f;
  for (int i = tid; i < H_ * S_ * HD_; i += blockDim.x * gridDim.x)
    centers[i] = base_centers[i] + center_deltas[i] * move;
  if (tid < H_ * S_) {
    float sc = __expf(log_scales[tid]);
    sc = fminf(fmaxf(sc, 1e-4f), 5.f);
    float am = __expf(log_amps[tid]);
    am = fminf(fmaxf(am, 1e-6f), 10.f);
    inv_var[tid] = 1.f / (sc * sc + 1e-8f);
    eff_amps[tid] = (am > 0.001f) ? am : 0.f;
  }
  if (tid == 0) {
    float t = fminf(fmaxf(temperature[0], 0.01f), 10.f);
    inv_temp[0] = 1.f / t;
  }
}

// ---------------- fp32 GEMM: C[M,N] = A[M,K] @ Bw[N,K]^T, 128x128 tile ----------------
__global__ __launch_bounds__(256) void gemm128(const float* __restrict__ A,
                                               const float* __restrict__ Bw,
                                               float* __restrict__ C,
                                               int M, int N, int K) {
  __shared__ float As[16][132];
  __shared__ float Bs[16][132];
  const int tid = threadIdx.x;
  const int m0 = blockIdx.y * 128;
  const int n0 = blockIdx.x * 128;
  const int tx = tid & 15;
  const int ty = tid >> 4;
  float acc[8][8] = {};
  for (int k0 = 0; k0 < K; k0 += 16) {
#pragma unroll
    for (int l = 0; l < 2; ++l) {
      int idx = (tid + l * 256) * 4;
      int m = idx >> 4, kk = idx & 15;
      float4 v = *(const float4*)(A + (size_t)(m0 + m) * K + k0 + kk);
      As[kk + 0][m] = v.x; As[kk + 1][m] = v.y; As[kk + 2][m] = v.z; As[kk + 3][m] = v.w;
      float4 w = *(const float4*)(Bw + (size_t)(n0 + m) * K + k0 + kk);
      Bs[kk + 0][m] = w.x; Bs[kk + 1][m] = w.y; Bs[kk + 2][m] = w.z; Bs[kk + 3][m] = w.w;
    }
    __syncthreads();
#pragma unroll
    for (int kk = 0; kk < 16; ++kk) {
      float4 a0 = *(const float4*)&As[kk][ty * 4];
      float4 a1 = *(const float4*)&As[kk][64 + ty * 4];
      float4 b0 = *(const float4*)&Bs[kk][tx * 4];
      float4 b1 = *(const float4*)&Bs[kk][64 + tx * 4];
      float av[8] = {a0.x, a0.y, a0.z, a0.w, a1.x, a1.y, a1.z, a1.w};
      float bv[8] = {b0.x, b0.y, b0.z, b0.w, b1.x, b1.y, b1.z, b1.w};
#pragma unroll
      for (int i = 0; i < 8; ++i)
#pragma unroll
        for (int j = 0; j < 8; ++j)
          acc[i][j] += av[i] * bv[j];
    }
    __syncthreads();
  }
#pragma unroll
  for (int i = 0; i < 8; ++i) {
    int row = m0 + ((i >> 2) * 64) + ty * 4 + (i & 3);
#pragma unroll
    for (int jc = 0; jc < 2; ++jc) {
      float4 v = make_float4(acc[i][jc * 4 + 0], acc[i][jc * 4 + 1],
                             acc[i][jc * 4 + 2], acc[i][jc * 4 + 3]);
      *(float4*)(C + (size_t)row * N + n0 + jc * 64 + tx * 4) = v;
    }
  }
}

// ---------------- gaussian kernel weights: q_w (× 1/temp), k_w ----------------
__global__ __launch_bounds__(256) void k_gauss(const float* __restrict__ qkv,
                                               const float* __restrict__ centers,
                                               const float* __restrict__ inv_var,
                                               const float* __restrict__ eff_amps,
                                               const float* __restrict__ inv_temp,
                                               float* __restrict__ qw,
                                               float* __restrict__ kw) {
  int gid = blockIdx.x * blockDim.x + threadIdx.x;
  if (gid >= B_ * T_ * H_ * S_) return;
  int s = gid & 15;
  int h = (gid >> 4) & 7;
  int bt = gid >> 7;  // b*T + t
  const float* qrow = qkv + (size_t)bt * 1536 + h * 64;
  const float* krow = qrow + 512;
  const float* c = centers + (h * 16 + s) * 64;
  float qd = 0.f, kd = 0.f;
#pragma unroll
  for (int d = 0; d < 64; d += 4) {
    float4 cv = *(const float4*)(c + d);
    float4 qv = *(const float4*)(qrow + d);
    float4 kv = *(const float4*)(krow + d);
    float t;
    t = qv.x - cv.x; qd += t * t;
    t = qv.y - cv.y; qd += t * t;
    t = qv.z - cv.z; qd += t * t;
    t = qv.w - cv.w; qd += t * t;
    t = kv.x - cv.x; kd += t * t;
    t = kv.y - cv.y; kd += t * t;
    t = kv.z - cv.z; kd += t * t;
    t = kv.w - cv.w; kd += t * t;
  }
  qd = fminf(qd, 100.f);
  kd = fminf(kd, 100.f);
  float iv = inv_var[h * 16 + s];
  float ea = eff_amps[h * 16 + s];
  qw[gid] = __expf(-0.5f * qd * iv) * ea * inv_temp[0];
  kw[gid] = __expf(-0.5f * kd * iv) * ea;
}

__device__ __forceinline__ float dot16(const float4 q[4], const float4 k[4]) {
  return q[0].x * k[0].x + q[0].y * k[0].y + q[0].z * k[0].z + q[0].w * k[0].w +
         q[1].x * k[1].x + q[1].y * k[1].y + q[1].z * k[1].z + q[1].w * k[1].w +
         q[2].x * k[2].x + q[2].y * k[2].y + q[2].z * k[2].z + q[2].w * k[2].w +
         q[3].x * k[3].x + q[3].y * k[3].y + q[3].z * k[3].z + q[3].w * k[3].w;
}

// ---------------- fused attention: logits -> softmax -> attn write + PV ----------------
// grid: B * (T/ROWS); block 256. Two passes over j; logits recomputed in pass 2.
__global__ __launch_bounds__(256) void k_attn(const float* __restrict__ qkv,
                                              const float* __restrict__ qw_g,
                                              const float* __restrict__ kw_g,
                                              float* __restrict__ attn,
                                              float* __restrict__ out_pre) {
  const int wg = blockIdx.x;
  const int b = wg >> 7;
  const int i0 = (wg & 127) * ROWS;
  const int tid = threadIdx.x;

  __shared__ float qw_l[ROWS][H_ * S_];  // 4 KB
  __shared__ float tile[ROWS][H_][JT];   // 32 KB (attn values in pass 2)

  {
    float4 v = *(const float4*)(qw_g + (size_t)(b * T_ + i0) * (H_ * S_) + tid * 4);
    *(float4*)(&qw_l[0][0] + tid * 4) = v;
  }
  __syncthreads();

  const int h = tid >> 5;   // 0..7
  const int jq = tid & 31;  // 0..31
  const float* kw_b = kw_g + (size_t)b * T_ * (H_ * S_);

  float m_r[ROWS], s_r[ROWS];
#pragma unroll
  for (int r = 0; r < ROWS; ++r) { m_r[r] = -1e30f; s_r[r] = 0.f; }

  // ---- PASS 1: online max/sum per (row, h); no LDS, no barriers ----
  for (int jt = 0; jt < T_ / JT; ++jt) {
    const int j0 = jt * JT;
    float4 kw4[4][4];
#pragma unroll
    for (int u = 0; u < 4; ++u) {
      const float* kp = kw_b + ((size_t)(j0 + jq * 4 + u) * H_ + h) * S_;
      kw4[u][0] = *(const float4*)(kp);
      kw4[u][1] = *(const float4*)(kp + 4);
      kw4[u][2] = *(const float4*)(kp + 8);
      kw4[u][3] = *(const float4*)(kp + 12);
    }
#pragma unroll
    for (int r = 0; r < ROWS; ++r) {
      const float* qp = &qw_l[r][h * S_];
      float4 q4[4];
      q4[0] = *(const float4*)(qp);
      q4[1] = *(const float4*)(qp + 4);
      q4[2] = *(const float4*)(qp + 8);
      q4[3] = *(const float4*)(qp + 12);
      float lg[4];
#pragma unroll
      for (int u = 0; u < 4; ++u) lg[u] = dot16(q4, kw4[u]);
      float tmax = fmaxf(fmaxf(lg[0], lg[1]), fmaxf(lg[2], lg[3]));
#pragma unroll
      for (int o = 1; o < 32; o <<= 1) tmax = fmaxf(tmax, __shfl_xor(tmax, o));
      float mnew = fmaxf(m_r[r], tmax);
      float ts = __expf(lg[0] - mnew) + __expf(lg[1] - mnew) +
                 __expf(lg[2] - mnew) + __expf(lg[3] - mnew);
#pragma unroll
      for (int o = 1; o < 32; o <<= 1) ts += __shfl_xor(ts, o);
      s_r[r] = s_r[r] * __expf(m_r[r] - mnew) + ts;
      m_r[r] = mnew;
    }
  }
#pragma unroll
  for (int r = 0; r < ROWS; ++r) s_r[r] = 1.f / s_r[r];

  // ---- PASS 2: recompute logits -> attn values; write attn; accumulate PV ----
  const int d0 = (tid & 31) * 2;
  const float* v_b = qkv + (size_t)b * T_ * 1536 + 1024 + h * 64 + d0;
  float accv[ROWS][2];
#pragma unroll
  for (int r = 0; r < ROWS; ++r) { accv[r][0] = 0.f; accv[r][1] = 0.f; }
  float* attn_b = attn + (size_t)(b * T_ + i0) * (T_ * H_);

  for (int jt = 0; jt < T_ / JT; ++jt) {
    const int j0 = jt * JT;
    float4 kw4[4][4];
#pragma unroll
    for (int u = 0; u < 4; ++u) {
      const float* kp = kw_b + ((size_t)(j0 + jq * 4 + u) * H_ + h) * S_;
      kw4[u][0] = *(const float4*)(kp);
      kw4[u][1] = *(const float4*)(kp + 4);
      kw4[u][2] = *(const float4*)(kp + 8);
      kw4[u][3] = *(const float4*)(kp + 12);
    }
#pragma unroll
    for (int r = 0; r < ROWS; ++r) {
      const float* qp = &qw_l[r][h * S_];
      float4 q4[4];
      q4[0] = *(const float4*)(qp);
      q4[1] = *(const float4*)(qp + 4);
      q4[2] = *(const float4*)(qp + 8);
      q4[3] = *(const float4*)(qp + 12);
      float a0 = __expf(dot16(q4, kw4[0]) - m_r[r]) * s_r[r];
      float a1 = __expf(dot16(q4, kw4[1]) - m_r[r]) * s_r[r];
      float a2 = __expf(dot16(q4, kw4[2]) - m_r[r]) * s_r[r];
      float a3 = __expf(dot16(q4, kw4[3]) - m_r[r]) * s_r[r];
      *(float4*)&tile[r][h][jq * 4] = make_float4(a0, a1, a2, a3);
    }
    __syncthreads();
    // write attn tile to global (coalesced float4; LDS gather is 2-way-conflict free)
#pragma unroll
    for (int l = 0; l < 8; ++l) {
      int flat = (l * 256 + tid) * 4;  // 0..8191
      int r = flat >> 10;
      int rem = flat & 1023;     // jl*8 + h
      int jl = rem >> 3;
      int h0 = rem & 7;          // 0 or 4
      float4 v;
      v.x = tile[r][h0 + 0][jl];
      v.y = tile[r][h0 + 1][jl];
      v.z = tile[r][h0 + 2][jl];
      v.w = tile[r][h0 + 3][jl];
      *(float4*)(attn_b + (size_t)r * (T_ * H_) + (size_t)j0 * H_ + rem) = v;
    }
    // PV accumulation from the LDS attn tile
#pragma unroll
    for (int q = 0; q < JT / 4; ++q) {
      int j = j0 + q * 4;
      const float* vp = v_b + (size_t)j * 1536;
      float2 v0 = *(const float2*)(vp);
      float2 v1 = *(const float2*)(vp + 1536);
      float2 v2 = *(const float2*)(vp + 3072);
      float2 v3 = *(const float2*)(vp + 4608);
#pragma unroll
      for (int r = 0; r < ROWS; ++r) {
        float4 a4 = *(const float4*)&tile[r][h][q * 4];
        accv[r][0] += a4.x * v0.x + a4.y * v1.x + a4.z * v2.x + a4.w * v3.x;
        accv[r][1] += a4.x * v0.y + a4.y * v1.y + a4.z * v2.y + a4.w * v3.y;
      }
    }
    __syncthreads();
  }
#pragma unroll
  for (int r = 0; r < ROWS; ++r) {
    float2 o;
    o.x = accv[r][0];
    o.y = accv[r][1];
    *(float2*)(out_pre + (size_t)(b * T_ + i0 + r) * D_ + h * HD_ + d0) = o;
  }
}

extern "C" void kernel_launch(void* const* d_in, const int* in_sizes, int n_in,
                              void* d_out, int out_size, void* d_ws, size_t ws_size,
                              hipStream_t stream) {
  const float* x = (const float*)d_in[0];
  const float* qkv_w = (const float*)d_in[1];
  const float* out_w = (const float*)d_in[2];
  const float* base_c = (const float*)d_in[3];
  const float* deltas = (const float*)d_in[4];
  const float* log_sc = (const float*)d_in[5];
  const float* log_am = (const float*)d_in[6];
  const float* move_p = (const float*)d_in[7];
  const float* temp = (const float*)d_in[8];

  float* out = (float*)d_out;                    // B*T*D
  float* attn = out + (size_t)B_ * T_ * D_;      // B*T*T*H

  float* ws = (float*)d_ws;
  float* qkv = ws;                                          // 6,291,456
  float* qw = qkv + (size_t)B_ * T_ * 3 * D_;               // 524,288
  float* kw = qw + (size_t)B_ * T_ * H_ * S_;               // 524,288
  float* out_pre = kw + (size_t)B_ * T_ * H_ * S_;          // 2,097,152
  float* centers = out_pre + (size_t)B_ * T_ * D_;          // 8,192
  float* inv_var = centers + H_ * S_ * HD_;                 // 128
  float* eff_amps = inv_var + H_ * S_;                      // 128
  float* inv_temp = eff_amps + H_ * S_;                     // 1

  k_params<<<32, 256, 0, stream>>>(base_c, deltas, log_sc, log_am, move_p, temp,
                                   centers, inv_var, eff_amps, inv_temp);
  dim3 g1(1536 / 128, 4096 / 128);
  gemm128<<<g1, 256, 0, stream>>>(x, qkv_w, qkv, B_ * T_, 3 * D_, D_);
  k_gauss<<<(B_ * T_ * H_ * S_) / 256, 256, 0, stream>>>(qkv, centers, inv_var,
                                                         eff_amps, inv_temp, qw, kw);
  k_attn<<<B_ * (T_ / ROWS), 256, 0, stream>>>(qkv, qw, kw, attn, out_pre);
  dim3 g2(512 / 128, 4096 / 128);
  gemm128<<<g2, 256, 0, stream>>>(out_pre, out_w, out, B_ * T_, D_, D_);
}